// Round 11
// baseline (316.442 us; speedup 1.0000x reference)
//
#include <hip/hip_runtime.h>
#include <hip/hip_bf16.h>
#include <cstddef>
#include <cstdint>

typedef __attribute__((ext_vector_type(8))) short short8;   // 8 bf16 (4 VGPR)
typedef __attribute__((ext_vector_type(4))) float f32x4;    // MFMA C/D frag
typedef __attribute__((ext_vector_type(4))) unsigned short us4;
typedef __attribute__((ext_vector_type(8))) unsigned short us8;

constexpr int BS = 2;     // batch
constexpr int S  = 2048;
constexpr int D  = 1024;
constexpr int H  = 16;
constexpr int HD = 64;
constexpr int BH = BS * H;                  // 32
constexpr float QSCALE = 0.18033688011112042f;  // 0.125 * log2(e)

// f32 -> bf16 round-to-nearest-even (scalar)
__device__ __forceinline__ unsigned short f2bf(float x) {
    unsigned u = __builtin_bit_cast(unsigned, x);
    u += 0x7fffu + ((u >> 16) & 1u);
    return (unsigned short)(u >> 16);
}

// packed f32 pair -> 2 bf16 in one u32 (lo = a, hi = b)
__device__ __forceinline__ unsigned pkbf(float a, float b) {
    unsigned r;
    asm("v_cvt_pk_bf16_f32 %0, %1, %2" : "=v"(r) : "v"(a), "v"(b));
    return r;
}

// native 2^x
__device__ __forceinline__ float fexp2(float x) {
    float r; asm("v_exp_f32 %0, %1" : "=v"(r) : "v"(x)); return r;
}

__device__ __forceinline__ f32x4 MFMA(short8 a, short8 b, f32x4 c) {
    return __builtin_amdgcn_mfma_f32_16x16x32_bf16(a, b, c, 0, 0, 0);
}

// ---------------------------------------------------------------------------
// Async staging (m97-style): tiles of 128-B rows, LINEAR LDS.
// CH = number of 4KB chunks (4 => 16KB tile, 2 => 8KB tile).
// ---------------------------------------------------------------------------
template<int CH>
__device__ __forceinline__ void stage_async(char* lds, const char* g,
                                            int gstride, int tid) {
    const int w = tid >> 6, l = tid & 63;
#pragma unroll
    for (int i = 0; i < CH; ++i) {
        const int fb = i * 4096 + w * 1024;          // wave-uniform
        const int f  = fb + l * 16;
        const int row = f >> 7, colb = f & 127;
        __builtin_amdgcn_global_load_lds(
            (const __attribute__((address_space(1))) uint32_t*)(g + (size_t)row * gstride + colb),
            (__attribute__((address_space(3))) uint32_t*)(lds + fb),
            16, 0, 0);
    }
}

// linear fragment load
__device__ __forceinline__ short8 fldl(const char* lds, int row, int kb) {
    return *(const short8*)(lds + row * 128 + kb);
}

// swizzled fragment load (attention P tile only)
__device__ __forceinline__ short8 fld(const char* lds, int row, int kb) {
    return *(const short8*)(lds + row * 128 + (kb ^ ((row & 7) << 4)));
}

// ---------------------------------------------------------------------------
// k_prep: fused input conversion + weight transposes.
// ---------------------------------------------------------------------------
__global__ __launch_bounds__(256) void k_prep(const float* __restrict__ x,
                                              unsigned short* __restrict__ xb,
                                              const float* __restrict__ Wq,
                                              unsigned short* __restrict__ wqT,
                                              const float* __restrict__ Wo,
                                              unsigned short* __restrict__ woT) {
    __shared__ float t[64][65];
    const int bid = blockIdx.x;
    if (bid < 4096) {
        const int i = bid * 256 + threadIdx.x;
        f32x4 v = ((const f32x4*)x)[i];
        us4 o = {f2bf(v[0]), f2bf(v[1]), f2bf(v[2]), f2bf(v[3])};
        ((us4*)xb)[i] = o;
        return;
    }
    const float* src; unsigned short* dst; int N, bx, by;
    if (bid < 4864) { const int b2 = bid - 4096; src = Wq; dst = wqT; N = 3072; bx = b2 % 48; by = b2 / 48; }
    else            { const int b3 = bid - 4864; src = Wo; dst = woT; N = 1024; bx = b3 % 16; by = b3 / 16; }
    const int K = 1024;
    const int k0 = by * 64, n0 = bx * 64;
    const int rr = threadIdx.x >> 4, c4 = (threadIdx.x & 15) * 4;
#pragma unroll
    for (int u = 0; u < 4; ++u) {
        int r = rr + u * 16;
        f32x4 v = *(const f32x4*)(src + (size_t)(k0 + r) * N + n0 + c4);
        t[r][c4 + 0] = v[0]; t[r][c4 + 1] = v[1];
        t[r][c4 + 2] = v[2]; t[r][c4 + 3] = v[3];
    }
    __syncthreads();
#pragma unroll
    for (int u = 0; u < 4; ++u) {
        int r = rr + u * 16;
        us4 o = {f2bf(t[c4 + 0][r]), f2bf(t[c4 + 1][r]),
                 f2bf(t[c4 + 2][r]), f2bf(t[c4 + 3][r])};
        *(us4*)(dst + (size_t)(n0 + r) * K + k0 + c4) = o;
    }
}

// ---------------------------------------------------------------------------
// GEMM core (m97 structure): 128(n) x 128(m) tile, BK=64, 4 waves (2n x 2m).
// acc[i][j][r] = C[m = mBase + j*16 + li][n = nBase + i*16 + g*4 + r]
// ---------------------------------------------------------------------------
__device__ __forceinline__ void gemm_core(const char* Ag, const char* Bg,
                                          char* lA, char* lB, int tid,
                                          f32x4 (&acc)[4][4]) {
    const int l = tid & 63, g = l >> 4, li = l & 15;
    const int w = tid >> 6, wn = w >> 1, wm = w & 1;
    for (int k0 = 0; k0 < 1024; k0 += 64) {
        __syncthreads();
        stage_async<4>(lA, Ag + k0 * 2, 2048, tid);
        stage_async<4>(lB, Bg + k0 * 2, 2048, tid);
        __syncthreads();   // compiler drains vmcnt(0) before barrier
#pragma unroll
        for (int kf = 0; kf < 2; ++kf) {
            short8 a[4], b[4];
#pragma unroll
            for (int i = 0; i < 4; ++i) a[i] = fldl(lA, wn * 64 + i * 16 + li, kf * 64 + g * 16);
#pragma unroll
            for (int i = 0; i < 4; ++i) b[i] = fldl(lB, wm * 64 + i * 16 + li, kf * 64 + g * 16);
#pragma unroll
            for (int i = 0; i < 4; ++i)
#pragma unroll
                for (int j = 0; j < 4; ++j) acc[i][j] = MFMA(a[i], b[j], acc[i][j]);
        }
    }
}

// ---------------------------------------------------------------------------
// QKV projection (round-9 verified).
// ---------------------------------------------------------------------------
__global__ __launch_bounds__(256) void k_qkv(const unsigned short* __restrict__ WqT,
                                             const unsigned short* __restrict__ xb,
                                             const float* __restrict__ bias,
                                             unsigned short* __restrict__ Qf,
                                             unsigned short* __restrict__ Kf,
                                             unsigned short* __restrict__ Vf) {
    __shared__ alignas(16) char lds[32768];
    char* lA = lds;
    char* lB = lds + 16384;
    const int tid = threadIdx.x;
    f32x4 acc[4][4] = {};
    const char* Ag = (const char*)(WqT + (size_t)blockIdx.y * 128 * 1024);
    const char* Bg = (const char*)(xb  + (size_t)blockIdx.x * 128 * 1024);
    gemm_core(Ag, Bg, lA, lB, tid, acc);

    const int l = tid & 63, g = l >> 4, li = l & 15;
    const int w = tid >> 6, wn = w >> 1, wm = w & 1;
    const int nWbase = blockIdx.y * 128 + wn * 64;   // wave n-window (64-aligned)
    const int mBaseW = blockIdx.x * 128 + wm * 64;   // wave m-window
    const int r2w = nWbase % 192;
    const int ttw = r2w >> 6;                        // wave-uniform type
    const int hW  = nWbase / 192;
    const int bbW = mBaseW >> 11;                    // batch uniform per block
    const int bhW = bbW * H + hW;

    __syncthreads();   // gemm's last LDS reads must finish before reuse

    if (ttw == 2) {
        // ---- V path: LDS transpose to [d][s] (bf16, XOR-swizzled) ----
        char* buf = lds + w * 8192;   // private 8KB per wave
#pragma unroll
        for (int i = 0; i < 4; ++i)
#pragma unroll
            for (int j = 0; j < 4; ++j) {
                const int n0 = nWbase + i * 16 + g * 4;
                const f32x4 b4 = *(const f32x4*)(bias + n0);
                f32x4 v = acc[i][j];
                v += b4;
                const int sl = j * 16 + li;
#pragma unroll
                for (int r = 0; r < 4; ++r) {
                    const int d = i * 16 + g * 4 + r;
                    *(unsigned short*)(buf + ((d * 128 + sl * 2) ^ ((d & 7) << 4)))
                        = f2bf(v[r]);
                }
            }
#pragma unroll
        for (int it = 0; it < 8; ++it) {
            const int d = l;
            us8 val = *(const us8*)(buf + ((d * 128 + it * 16) ^ ((d & 7) << 4)));
            const int s = (mBaseW & (S - 1)) + it * 8;
            size_t e = ((((size_t)bhW * 32 + (s >> 6)) * 2 + ((s >> 5) & 1)) * 4
                        + (d >> 4)) * 512
                     + ((s >> 3) & 3) * 128 + (d & 15) * 8;
            *(us8*)(Vf + e) = val;
        }
        return;
    }

    // ---- Q/K path: direct scatter ----
#pragma unroll
    for (int i = 0; i < 4; ++i)
#pragma unroll
        for (int j = 0; j < 4; ++j) {
            const int n0 = nWbase + i * 16 + g * 4;
            const int m  = mBaseW + j * 16 + li;
            const int s = m & (S - 1);
            const int d0 = (r2w & 63) + i * 16 + g * 4;
            f32x4 v = acc[i][j];
            const f32x4 b4 = *(const f32x4*)(bias + n0);
            v += b4;
            if (ttw == 0) {
                v[0] *= QSCALE; v[1] *= QSCALE; v[2] *= QSCALE; v[3] *= QSCALE;
                us4 o = {f2bf(v[0]), f2bf(v[1]), f2bf(v[2]), f2bf(v[3])};
                size_t e = (((size_t)bhW * 128 + (s >> 4)) * 2 + (d0 >> 5)) * 512
                         + (((d0 & 31) >> 3) * 16 + (s & 15)) * 8 + (d0 & 7);
                *(us4*)(Qf + e) = o;
            } else {
                us4 o = {f2bf(v[0]), f2bf(v[1]), f2bf(v[2]), f2bf(v[3])};
                size_t e = ((((size_t)bhW * 32 + (s >> 6)) * 2 + (d0 >> 5)) * 4
                            + ((s >> 4) & 3)) * 512
                         + (((d0 & 31) >> 3) * 16 + (s & 15)) * 8 + (d0 & 7);
                *(us4*)(Kf + e) = o;
            }
        }
}

// ---------------------------------------------------------------------------
// Output projection (round-9 verified): 64(m) x 128(n), grid (64, 8).
// acc[i][j][r] = C[m = bx*64 + wm*32 + j*16 + li][n = by*128 + wn*64 + i*16 + g*4 + r]
// ---------------------------------------------------------------------------
__global__ __launch_bounds__(256) void k_out(const unsigned short* __restrict__ WoT,
                                             const unsigned short* __restrict__ vtb,
                                             const float* __restrict__ bias,
                                             float* __restrict__ outp) {
    __shared__ alignas(16) char lA[16384];   // 128 n-rows x 64 k
    __shared__ alignas(16) char lB[8192];    // 64 m-rows x 64 k
    const int tid = threadIdx.x;
    const int l = tid & 63, g = l >> 4, li = l & 15;
    const int w = tid >> 6, wn = w >> 1, wm = w & 1;
    const char* Ag = (const char*)(WoT + (size_t)blockIdx.y * 128 * 1024);
    const char* Bg = (const char*)(vtb + (size_t)blockIdx.x * 64 * 1024);

    f32x4 acc[4][2] = {};
    for (int k0 = 0; k0 < 1024; k0 += 64) {
        __syncthreads();
        stage_async<4>(lA, Ag + k0 * 2, 2048, tid);
        stage_async<2>(lB, Bg + k0 * 2, 2048, tid);
        __syncthreads();
#pragma unroll
        for (int kf = 0; kf < 2; ++kf) {
            short8 a[4], b[2];
#pragma unroll
            for (int i = 0; i < 4; ++i) a[i] = fldl(lA, wn * 64 + i * 16 + li, kf * 64 + g * 16);
#pragma unroll
            for (int j = 0; j < 2; ++j) b[j] = fldl(lB, wm * 32 + j * 16 + li, kf * 64 + g * 16);
#pragma unroll
            for (int i = 0; i < 4; ++i)
#pragma unroll
                for (int j = 0; j < 2; ++j) acc[i][j] = MFMA(a[i], b[j], acc[i][j]);
        }
    }

#pragma unroll
    for (int i = 0; i < 4; ++i)
#pragma unroll
        for (int j = 0; j < 2; ++j) {
            const int n0 = blockIdx.y * 128 + wn * 64 + i * 16 + g * 4;
            const int m  = blockIdx.x * 64 + wm * 32 + j * 16 + li;
            f32x4 v = acc[i][j];
            const f32x4 b4 = *(const f32x4*)(bias + n0);
            v += b4;
            *(f32x4*)(outp + (size_t)m * D + n0) = v;
        }
}

// ---------------------------------------------------------------------------
// Attention helpers
// ---------------------------------------------------------------------------
__device__ __forceinline__ void ldfr(short8 (&b)[8], const short8* base, int l) {
#pragma unroll
    for (int f = 0; f < 8; ++f) b[f] = base[f * 64 + l];
}

// ---------------------------------------------------------------------------
// k_attn (round-9 structure + scheduling upgrades):
//   pass 1: denominator, DUAL-K register buffers, prefetch distance 2.
//   pass 2: probs + PV in one loop (stores embedded with compute — the
//           round-10 lesson); K(t+1) load issued BEFORE the store burst,
//           stores deferred to fill the load-latency window.
// Grid 1024 (XCD-swizzled), 16 q-rows/wave, 4 waves/SIMD.
// ---------------------------------------------------------------------------
__global__ __launch_bounds__(256, 4) void k_attn(const unsigned short* __restrict__ Qf,
                                                 const unsigned short* __restrict__ Kf,
                                                 const unsigned short* __restrict__ Vf,
                                                 float* __restrict__ attn,
                                                 unsigned short* __restrict__ vtb) {
    __shared__ alignas(16) char lP[8192];
    const int tid = threadIdx.x;
    const int w = tid >> 6, l = tid & 63, g = l >> 4, li = l & 15;
    const int wid = (blockIdx.x & 7) * 128 + (blockIdx.x >> 3);   // XCD swizzle
    const int bh = wid >> 5, bx = wid & 31;
    const int b = bh >> 4, h = bh & 15;
    const int q0 = bx * 64 + w * 16;
    char* pb = lP + w * 2048;   // per-wave [16 q][64 kv] bf16, swizzled

    const short8* Q8 = (const short8*)Qf;
    const short8* Kt8 = (const short8*)Kf + (size_t)bh * 16384;
    const short8* Vt8 = (const short8*)Vf + (size_t)bh * 16384;
    float* attnb = attn + (size_t)bh * S * S;

    short8 qfr[2];
#pragma unroll
    for (int kf = 0; kf < 2; ++kf)
        qfr[kf] = Q8[(((size_t)bh * 128 + (q0 >> 4)) * 2 + kf) * 64 + l];

    // ---- pass 1: denominator, dual-K prefetch (distance 2) ----
    float run = 0.f;
    {
        short8 ka[8], kb[8];
        ldfr(ka, Kt8, l);
        ldfr(kb, Kt8 + 512, l);
        for (int t = 0; t < 32; t += 2) {
            {
                f32x4 sc[4] = {};
                __builtin_amdgcn_s_setprio(1);
#pragma unroll
                for (int kf = 0; kf < 2; ++kf)
#pragma unroll
                    for (int i = 0; i < 4; ++i)
                        sc[i] = MFMA(ka[kf * 4 + i], qfr[kf], sc[i]);
                __builtin_amdgcn_s_setprio(0);
                if (t + 2 < 32) ldfr(ka, Kt8 + (t + 2) * 512, l);
                float part = 0.f;
#pragma unroll
                for (int i = 0; i < 4; ++i)
#pragma unroll
                    for (int r = 0; r < 4; ++r) part += fexp2(sc[i][r]);
                run += part;
            }
            {
                f32x4 sc[4] = {};
                __builtin_amdgcn_s_setprio(1);
#pragma unroll
                for (int kf = 0; kf < 2; ++kf)
#pragma unroll
                    for (int i = 0; i < 4; ++i)
                        sc[i] = MFMA(kb[kf * 4 + i], qfr[kf], sc[i]);
                __builtin_amdgcn_s_setprio(0);
                if (t + 3 < 32) ldfr(kb, Kt8 + (t + 3) * 512, l);
                float part = 0.f;
#pragma unroll
                for (int i = 0; i < 4; ++i)
#pragma unroll
                    for (int r = 0; r < 4; ++r) part += fexp2(sc[i][r]);
                run += part;
            }
        }
    }
    run += __shfl_xor(run, 16);
    run += __shfl_xor(run, 32);
    const float invl = 1.0f / run;

    // ---- pass 2: probs + PV (stores embedded, deferred past K-load) ----
    f32x4 oacc[4] = {};   // [dfrag], D[d = df*16+g*4+r][q = li]
    short8 kv[8];
    ldfr(kv, Kt8, l);
    for (int t = 0; t < 32; ++t) {
        f32x4 sc[4] = {};
        __builtin_amdgcn_s_setprio(1);
#pragma unroll
        for (int kf = 0; kf < 2; ++kf)
#pragma unroll
            for (int i = 0; i < 4; ++i)
                sc[i] = MFMA(kv[kf * 4 + i], qfr[kf], sc[i]);
        __builtin_amdgcn_s_setprio(0);
        ldfr(kv, Vt8 + t * 512, l);   // V(t) in flight under exp/LDS phase

        f32x4 p[4];
#pragma unroll
        for (int i = 0; i < 4; ++i) {
#pragma unroll
            for (int r = 0; r < 4; ++r) p[i][r] = fexp2(sc[i][r]) * invl;
            uint2 o = {pkbf(p[i][0], p[i][1]), pkbf(p[i][2], p[i][3])};
            *(uint2*)(pb + li * 128 + ((i * 32 + g * 8) ^ ((li & 7) << 4))) = o;
        }
        short8 pa[2];
#pragma unroll
        for (int kvf = 0; kvf < 2; ++kvf)
            pa[kvf] = fld(pb, li, kvf * 64 + g * 16);
        __builtin_amdgcn_s_setprio(1);
#pragma unroll
        for (int kvf = 0; kvf < 2; ++kvf)
#pragma unroll
            for (int df = 0; df < 4; ++df)
                oacc[df] = MFMA(kv[kvf * 4 + df], pa[kvf], oacc[df]);
        __builtin_amdgcn_s_setprio(0);
        if (t < 31) ldfr(kv, Kt8 + (t + 1) * 512, l);   // K(t+1) BEFORE stores

#pragma unroll
        for (int i = 0; i < 4; ++i)
            __builtin_nontemporal_store(
                p[i], (f32x4*)(attnb + (size_t)(q0 + li) * S + t * 64 + i * 16 + g * 4));
    }

    // vtb [B*S][H*HD] bf16
#pragma unroll
    for (int df = 0; df < 4; ++df) {
        const int qrow = q0 + li;
        const size_t m = (size_t)b * S + qrow;
        const int d0 = df * 16 + g * 4;
        uint2 o = {pkbf(oacc[df][0], oacc[df][1]),
                   pkbf(oacc[df][2], oacc[df][3])};
        *(uint2*)(vtb + m * D + h * HD + d0) = o;
    }
}

// ---------------------------------------------------------------------------
extern "C" void kernel_launch(void* const* d_in, const int* in_sizes, int n_in,
                              void* d_out, int out_size, void* d_ws, size_t ws_size,
                              hipStream_t stream) {
    const float* x     = (const float*)d_in[0];
    const float* W_qkv = (const float*)d_in[1];
    const float* b_qkv = (const float*)d_in[2];
    const float* W_out = (const float*)d_in[3];
    const float* b_out = (const float*)d_in[4];

    float* out  = (float*)d_out;                    // [B,S,D] f32
    float* attn = out + (size_t)BS * S * D;         // [B,H,S,S] f32

    char* ws = (char*)d_ws;
    unsigned short* xb   = (unsigned short*)(ws);                    // [4096][1024]
    unsigned short* wqT  = (unsigned short*)(ws + 8388608);          // [3072][1024]
    unsigned short* woT  = (unsigned short*)(ws + 14680064);         // [1024][1024]
    unsigned short* Qf   = (unsigned short*)(ws + 16777216);         // frag layout
    unsigned short* Kf   = (unsigned short*)(ws + 25165824);         // frag layout
    unsigned short* Vf   = (unsigned short*)(ws + 33554432);         // frag layout
    unsigned short* vtb  = (unsigned short*)(ws + 41943040);         // [4096][1024]

    k_prep<<<5120, 256, 0, stream>>>(x, xb, W_qkv, wqT, W_out, woT);
    k_qkv<<<dim3(32, 24), 256, 0, stream>>>(wqT, xb, b_qkv, Qf, Kf, Vf);
    k_attn<<<1024, 256, 0, stream>>>(Qf, Kf, Vf, attn, vtb);
    k_out<<<dim3(64, 8), 256, 0, stream>>>(woT, vtb, b_out, out);   // x=m(64), y=n(8)
}

// Round 12
// 244.549 us; speedup vs baseline: 1.2940x; 1.2940x over previous
//
#include <hip/hip_runtime.h>
#include <hip/hip_bf16.h>
#include <cstddef>
#include <cstdint>

typedef __attribute__((ext_vector_type(8))) short short8;   // 8 bf16 (4 VGPR)
typedef __attribute__((ext_vector_type(4))) float f32x4;    // MFMA C/D frag
typedef __attribute__((ext_vector_type(4))) unsigned short us4;
typedef __attribute__((ext_vector_type(8))) unsigned short us8;

constexpr int BS = 2;     // batch
constexpr int S  = 2048;
constexpr int D  = 1024;
constexpr int H  = 16;
constexpr int HD = 64;
constexpr int BH = BS * H;                  // 32
constexpr float QSCALE = 0.18033688011112042f;  // 0.125 * log2(e)

// f32 -> bf16 round-to-nearest-even (scalar)
__device__ __forceinline__ unsigned short f2bf(float x) {
    unsigned u = __builtin_bit_cast(unsigned, x);
    u += 0x7fffu + ((u >> 16) & 1u);
    return (unsigned short)(u >> 16);
}

// packed f32 pair -> 2 bf16 in one u32 (lo = a, hi = b)
__device__ __forceinline__ unsigned pkbf(float a, float b) {
    unsigned r;
    asm("v_cvt_pk_bf16_f32 %0, %1, %2" : "=v"(r) : "v"(a), "v"(b));
    return r;
}

// native 2^x
__device__ __forceinline__ float fexp2(float x) {
    float r; asm("v_exp_f32 %0, %1" : "=v"(r) : "v"(x)); return r;
}

__device__ __forceinline__ f32x4 MFMA(short8 a, short8 b, f32x4 c) {
    return __builtin_amdgcn_mfma_f32_16x16x32_bf16(a, b, c, 0, 0, 0);
}

// ---------------------------------------------------------------------------
// Async staging (m97-style): tiles of 128-B rows, LINEAR LDS.
// CH = number of 4KB chunks (4 => 16KB tile, 2 => 8KB tile).
// ---------------------------------------------------------------------------
template<int CH>
__device__ __forceinline__ void stage_async(char* lds, const char* g,
                                            int gstride, int tid) {
    const int w = tid >> 6, l = tid & 63;
#pragma unroll
    for (int i = 0; i < CH; ++i) {
        const int fb = i * 4096 + w * 1024;          // wave-uniform
        const int f  = fb + l * 16;
        const int row = f >> 7, colb = f & 127;
        __builtin_amdgcn_global_load_lds(
            (const __attribute__((address_space(1))) uint32_t*)(g + (size_t)row * gstride + colb),
            (__attribute__((address_space(3))) uint32_t*)(lds + fb),
            16, 0, 0);
    }
}

// linear fragment load
__device__ __forceinline__ short8 fldl(const char* lds, int row, int kb) {
    return *(const short8*)(lds + row * 128 + kb);
}

// swizzled fragment load (attention P tile only)
__device__ __forceinline__ short8 fld(const char* lds, int row, int kb) {
    return *(const short8*)(lds + row * 128 + (kb ^ ((row & 7) << 4)));
}

// ---------------------------------------------------------------------------
// k_prep: fused input conversion + weight transposes.
// ---------------------------------------------------------------------------
__global__ __launch_bounds__(256) void k_prep(const float* __restrict__ x,
                                              unsigned short* __restrict__ xb,
                                              const float* __restrict__ Wq,
                                              unsigned short* __restrict__ wqT,
                                              const float* __restrict__ Wo,
                                              unsigned short* __restrict__ woT) {
    __shared__ float t[64][65];
    const int bid = blockIdx.x;
    if (bid < 4096) {
        const int i = bid * 256 + threadIdx.x;
        f32x4 v = ((const f32x4*)x)[i];
        us4 o = {f2bf(v[0]), f2bf(v[1]), f2bf(v[2]), f2bf(v[3])};
        ((us4*)xb)[i] = o;
        return;
    }
    const float* src; unsigned short* dst; int N, bx, by;
    if (bid < 4864) { const int b2 = bid - 4096; src = Wq; dst = wqT; N = 3072; bx = b2 % 48; by = b2 / 48; }
    else            { const int b3 = bid - 4864; src = Wo; dst = woT; N = 1024; bx = b3 % 16; by = b3 / 16; }
    const int K = 1024;
    const int k0 = by * 64, n0 = bx * 64;
    const int rr = threadIdx.x >> 4, c4 = (threadIdx.x & 15) * 4;
#pragma unroll
    for (int u = 0; u < 4; ++u) {
        int r = rr + u * 16;
        f32x4 v = *(const f32x4*)(src + (size_t)(k0 + r) * N + n0 + c4);
        t[r][c4 + 0] = v[0]; t[r][c4 + 1] = v[1];
        t[r][c4 + 2] = v[2]; t[r][c4 + 3] = v[3];
    }
    __syncthreads();
#pragma unroll
    for (int u = 0; u < 4; ++u) {
        int r = rr + u * 16;
        us4 o = {f2bf(t[c4 + 0][r]), f2bf(t[c4 + 1][r]),
                 f2bf(t[c4 + 2][r]), f2bf(t[c4 + 3][r])};
        *(us4*)(dst + (size_t)(n0 + r) * K + k0 + c4) = o;
    }
}

// ---------------------------------------------------------------------------
// GEMM core (m97 structure): 128(n) x 128(m) tile, BK=64, 4 waves (2n x 2m).
// acc[i][j][r] = C[m = mBase + j*16 + li][n = nBase + i*16 + g*4 + r]
// ---------------------------------------------------------------------------
__device__ __forceinline__ void gemm_core(const char* Ag, const char* Bg,
                                          char* lA, char* lB, int tid,
                                          f32x4 (&acc)[4][4]) {
    const int l = tid & 63, g = l >> 4, li = l & 15;
    const int w = tid >> 6, wn = w >> 1, wm = w & 1;
    for (int k0 = 0; k0 < 1024; k0 += 64) {
        __syncthreads();
        stage_async<4>(lA, Ag + k0 * 2, 2048, tid);
        stage_async<4>(lB, Bg + k0 * 2, 2048, tid);
        __syncthreads();   // compiler drains vmcnt(0) before barrier
#pragma unroll
        for (int kf = 0; kf < 2; ++kf) {
            short8 a[4], b[4];
#pragma unroll
            for (int i = 0; i < 4; ++i) a[i] = fldl(lA, wn * 64 + i * 16 + li, kf * 64 + g * 16);
#pragma unroll
            for (int i = 0; i < 4; ++i) b[i] = fldl(lB, wm * 64 + i * 16 + li, kf * 64 + g * 16);
#pragma unroll
            for (int i = 0; i < 4; ++i)
#pragma unroll
                for (int j = 0; j < 4; ++j) acc[i][j] = MFMA(a[i], b[j], acc[i][j]);
        }
    }
}

// ---------------------------------------------------------------------------
// QKV projection (round-9 verified).
// ---------------------------------------------------------------------------
__global__ __launch_bounds__(256) void k_qkv(const unsigned short* __restrict__ WqT,
                                             const unsigned short* __restrict__ xb,
                                             const float* __restrict__ bias,
                                             unsigned short* __restrict__ Qf,
                                             unsigned short* __restrict__ Kf,
                                             unsigned short* __restrict__ Vf) {
    __shared__ alignas(16) char lds[32768];
    char* lA = lds;
    char* lB = lds + 16384;
    const int tid = threadIdx.x;
    f32x4 acc[4][4] = {};
    const char* Ag = (const char*)(WqT + (size_t)blockIdx.y * 128 * 1024);
    const char* Bg = (const char*)(xb  + (size_t)blockIdx.x * 128 * 1024);
    gemm_core(Ag, Bg, lA, lB, tid, acc);

    const int l = tid & 63, g = l >> 4, li = l & 15;
    const int w = tid >> 6, wn = w >> 1, wm = w & 1;
    const int nWbase = blockIdx.y * 128 + wn * 64;   // wave n-window (64-aligned)
    const int mBaseW = blockIdx.x * 128 + wm * 64;   // wave m-window
    const int r2w = nWbase % 192;
    const int ttw = r2w >> 6;                        // wave-uniform type
    const int hW  = nWbase / 192;
    const int bbW = mBaseW >> 11;                    // batch uniform per block
    const int bhW = bbW * H + hW;

    __syncthreads();   // gemm's last LDS reads must finish before reuse

    if (ttw == 2) {
        // ---- V path: LDS transpose to [d][s] (bf16, XOR-swizzled) ----
        char* buf = lds + w * 8192;   // private 8KB per wave
#pragma unroll
        for (int i = 0; i < 4; ++i)
#pragma unroll
            for (int j = 0; j < 4; ++j) {
                const int n0 = nWbase + i * 16 + g * 4;
                const f32x4 b4 = *(const f32x4*)(bias + n0);
                f32x4 v = acc[i][j];
                v += b4;
                const int sl = j * 16 + li;
#pragma unroll
                for (int r = 0; r < 4; ++r) {
                    const int d = i * 16 + g * 4 + r;
                    *(unsigned short*)(buf + ((d * 128 + sl * 2) ^ ((d & 7) << 4)))
                        = f2bf(v[r]);
                }
            }
#pragma unroll
        for (int it = 0; it < 8; ++it) {
            const int d = l;
            us8 val = *(const us8*)(buf + ((d * 128 + it * 16) ^ ((d & 7) << 4)));
            const int s = (mBaseW & (S - 1)) + it * 8;
            size_t e = ((((size_t)bhW * 32 + (s >> 6)) * 2 + ((s >> 5) & 1)) * 4
                        + (d >> 4)) * 512
                     + ((s >> 3) & 3) * 128 + (d & 15) * 8;
            *(us8*)(Vf + e) = val;
        }
        return;
    }

    // ---- Q/K path: direct scatter ----
#pragma unroll
    for (int i = 0; i < 4; ++i)
#pragma unroll
        for (int j = 0; j < 4; ++j) {
            const int n0 = nWbase + i * 16 + g * 4;
            const int m  = mBaseW + j * 16 + li;
            const int s = m & (S - 1);
            const int d0 = (r2w & 63) + i * 16 + g * 4;
            f32x4 v = acc[i][j];
            const f32x4 b4 = *(const f32x4*)(bias + n0);
            v += b4;
            if (ttw == 0) {
                v[0] *= QSCALE; v[1] *= QSCALE; v[2] *= QSCALE; v[3] *= QSCALE;
                us4 o = {f2bf(v[0]), f2bf(v[1]), f2bf(v[2]), f2bf(v[3])};
                size_t e = (((size_t)bhW * 128 + (s >> 4)) * 2 + (d0 >> 5)) * 512
                         + (((d0 & 31) >> 3) * 16 + (s & 15)) * 8 + (d0 & 7);
                *(us4*)(Qf + e) = o;
            } else {
                us4 o = {f2bf(v[0]), f2bf(v[1]), f2bf(v[2]), f2bf(v[3])};
                size_t e = ((((size_t)bhW * 32 + (s >> 6)) * 2 + (d0 >> 5)) * 4
                            + ((s >> 4) & 3)) * 512
                         + (((d0 & 31) >> 3) * 16 + (s & 15)) * 8 + (d0 & 7);
                *(us4*)(Kf + e) = o;
            }
        }
}

// ---------------------------------------------------------------------------
// Output projection (round-10 correctness-proven variant): 64(m) x 64(n)
// tiles, grid (64, 16) = 1024 blocks = 4/CU for latency hiding.
// acc[i][j][r] = C[m = bx*64 + wm*32 + j*16 + li][n = by*64 + wn*32 + i*16 + g*4 + r]
// grid: blockIdx.x -> m tiles (64), blockIdx.y -> n tiles (16).
// ---------------------------------------------------------------------------
__global__ __launch_bounds__(256) void k_out(const unsigned short* __restrict__ WoT,
                                             const unsigned short* __restrict__ vtb,
                                             const float* __restrict__ bias,
                                             float* __restrict__ outp) {
    __shared__ alignas(16) char lA[8192];    // 64 n-rows x 64 k
    __shared__ alignas(16) char lB[8192];    // 64 m-rows x 64 k
    const int tid = threadIdx.x;
    const int l = tid & 63, g = l >> 4, li = l & 15;
    const int w = tid >> 6, wn = w >> 1, wm = w & 1;
    const char* Ag = (const char*)(WoT + (size_t)blockIdx.y * 64 * 1024);
    const char* Bg = (const char*)(vtb + (size_t)blockIdx.x * 64 * 1024);

    f32x4 acc[2][2] = {};
    for (int k0 = 0; k0 < 1024; k0 += 64) {
        __syncthreads();
        stage_async<2>(lA, Ag + k0 * 2, 2048, tid);
        stage_async<2>(lB, Bg + k0 * 2, 2048, tid);
        __syncthreads();
#pragma unroll
        for (int kf = 0; kf < 2; ++kf) {
            short8 a[2], b[2];
#pragma unroll
            for (int i = 0; i < 2; ++i) a[i] = fldl(lA, wn * 32 + i * 16 + li, kf * 64 + g * 16);
#pragma unroll
            for (int j = 0; j < 2; ++j) b[j] = fldl(lB, wm * 32 + j * 16 + li, kf * 64 + g * 16);
#pragma unroll
            for (int i = 0; i < 2; ++i)
#pragma unroll
                for (int j = 0; j < 2; ++j) acc[i][j] = MFMA(a[i], b[j], acc[i][j]);
        }
    }

#pragma unroll
    for (int i = 0; i < 2; ++i)
#pragma unroll
        for (int j = 0; j < 2; ++j) {
            const int n0 = blockIdx.y * 64 + wn * 32 + i * 16 + g * 4;
            const int m  = blockIdx.x * 64 + wm * 32 + j * 16 + li;
            f32x4 v = acc[i][j];
            const f32x4 b4 = *(const f32x4*)(bias + n0);
            v += b4;
            *(f32x4*)(outp + (size_t)m * D + n0) = v;
        }
}

// ---------------------------------------------------------------------------
// Attention helpers
// ---------------------------------------------------------------------------
__device__ __forceinline__ void ldfr(short8 (&b)[8], const short8* base, int l) {
#pragma unroll
    for (int f = 0; f < 8; ++f) b[f] = base[f * 64 + l];
}

// ---------------------------------------------------------------------------
// k_attn (round-9 EXACT — verified 245 us config): fused denominator +
// prob/PV pass, 16 q-rows/wave, kv[8] time-shared, 4 waves/SIMD.
// Register budget ~115 VGPR fits the 128-cap of launch_bounds(256,4);
// rounds 10/11 proved any added ILP state spills and regresses.
// ---------------------------------------------------------------------------
__global__ __launch_bounds__(256, 4) void k_attn(const unsigned short* __restrict__ Qf,
                                                 const unsigned short* __restrict__ Kf,
                                                 const unsigned short* __restrict__ Vf,
                                                 float* __restrict__ attn,
                                                 unsigned short* __restrict__ vtb) {
    __shared__ alignas(16) char lP[8192];
    const int tid = threadIdx.x;
    const int w = tid >> 6, l = tid & 63, g = l >> 4, li = l & 15;
    const int wid = (blockIdx.x & 7) * 128 + (blockIdx.x >> 3);   // XCD swizzle
    const int bh = wid >> 5, bx = wid & 31;
    const int b = bh >> 4, h = bh & 15;
    const int q0 = bx * 64 + w * 16;
    char* pb = lP + w * 2048;   // per-wave [16 q][64 kv] bf16, swizzled

    const short8* Q8 = (const short8*)Qf;
    const short8* Kt8 = (const short8*)Kf + (size_t)bh * 16384;
    const short8* Vt8 = (const short8*)Vf + (size_t)bh * 16384;
    float* attnb = attn + (size_t)bh * S * S;

    short8 qfr[2];
#pragma unroll
    for (int kf = 0; kf < 2; ++kf)
        qfr[kf] = Q8[(((size_t)bh * 128 + (q0 >> 4)) * 2 + kf) * 64 + l];

    short8 kv[8];

    // ---- pass 1: denominator (register-resident) ----
    float run = 0.f;
    ldfr(kv, Kt8, l);
    for (int t = 0; t < 32; ++t) {
        f32x4 sc[4] = {};
        __builtin_amdgcn_s_setprio(1);
#pragma unroll
        for (int kf = 0; kf < 2; ++kf)
#pragma unroll
            for (int i = 0; i < 4; ++i)
                sc[i] = MFMA(kv[kf * 4 + i], qfr[kf], sc[i]);
        __builtin_amdgcn_s_setprio(0);
        if (t < 31) ldfr(kv, Kt8 + (t + 1) * 512, l);   // next K under exp phase
        float part = 0.f;
#pragma unroll
        for (int i = 0; i < 4; ++i)
#pragma unroll
            for (int r = 0; r < 4; ++r) part += fexp2(sc[i][r]);
        run += part;
    }
    run += __shfl_xor(run, 16);
    run += __shfl_xor(run, 32);
    const float invl = 1.0f / run;

    // ---- pass 2: probs + PV ----
    f32x4 oacc[4] = {};   // [dfrag], D[d = df*16+g*4+r][q = li]
    ldfr(kv, Kt8, l);
    for (int t = 0; t < 32; ++t) {
        f32x4 sc[4] = {};
        __builtin_amdgcn_s_setprio(1);
#pragma unroll
        for (int kf = 0; kf < 2; ++kf)
#pragma unroll
            for (int i = 0; i < 4; ++i)
                sc[i] = MFMA(kv[kf * 4 + i], qfr[kf], sc[i]);
        __builtin_amdgcn_s_setprio(0);
        ldfr(kv, Vt8 + t * 512, l);   // V(t) in flight under exp/store phase

#pragma unroll
        for (int i = 0; i < 4; ++i) {
            f32x4 p;
#pragma unroll
            for (int r = 0; r < 4; ++r) p[r] = fexp2(sc[i][r]) * invl;
            __builtin_nontemporal_store(
                p, (f32x4*)(attnb + (size_t)(q0 + li) * S + t * 64 + i * 16 + g * 4));
            uint2 o = {pkbf(p[0], p[1]), pkbf(p[2], p[3])};
            *(uint2*)(pb + li * 128 + ((i * 32 + g * 8) ^ ((li & 7) << 4))) = o;
        }
        short8 pa[2];
#pragma unroll
        for (int kvf = 0; kvf < 2; ++kvf)
            pa[kvf] = fld(pb, li, kvf * 64 + g * 16);
        __builtin_amdgcn_s_setprio(1);
#pragma unroll
        for (int kvf = 0; kvf < 2; ++kvf)
#pragma unroll
            for (int df = 0; df < 4; ++df)
                oacc[df] = MFMA(kv[kvf * 4 + df], pa[kvf], oacc[df]);
        __builtin_amdgcn_s_setprio(0);
        if (t < 31) ldfr(kv, Kt8 + (t + 1) * 512, l);   // K(t+1) in flight
    }

    // vtb [B*S][H*HD] bf16
#pragma unroll
    for (int df = 0; df < 4; ++df) {
        const int qrow = q0 + li;
        const size_t m = (size_t)b * S + qrow;
        const int d0 = df * 16 + g * 4;
        uint2 o = {pkbf(oacc[df][0], oacc[df][1]),
                   pkbf(oacc[df][2], oacc[df][3])};
        *(uint2*)(vtb + m * D + h * HD + d0) = o;
    }
}

// ---------------------------------------------------------------------------
extern "C" void kernel_launch(void* const* d_in, const int* in_sizes, int n_in,
                              void* d_out, int out_size, void* d_ws, size_t ws_size,
                              hipStream_t stream) {
    const float* x     = (const float*)d_in[0];
    const float* W_qkv = (const float*)d_in[1];
    const float* b_qkv = (const float*)d_in[2];
    const float* W_out = (const float*)d_in[3];
    const float* b_out = (const float*)d_in[4];

    float* out  = (float*)d_out;                    // [B,S,D] f32
    float* attn = out + (size_t)BS * S * D;         // [B,H,S,S] f32

    char* ws = (char*)d_ws;
    unsigned short* xb   = (unsigned short*)(ws);                    // [4096][1024]
    unsigned short* wqT  = (unsigned short*)(ws + 8388608);          // [3072][1024]
    unsigned short* woT  = (unsigned short*)(ws + 14680064);         // [1024][1024]
    unsigned short* Qf   = (unsigned short*)(ws + 16777216);         // frag layout
    unsigned short* Kf   = (unsigned short*)(ws + 25165824);         // frag layout
    unsigned short* Vf   = (unsigned short*)(ws + 33554432);         // frag layout
    unsigned short* vtb  = (unsigned short*)(ws + 41943040);         // [4096][1024]

    k_prep<<<5120, 256, 0, stream>>>(x, xb, W_qkv, wqT, W_out, woT);
    k_qkv<<<dim3(32, 24), 256, 0, stream>>>(wqT, xb, b_qkv, Qf, Kf, Vf);
    k_attn<<<1024, 256, 0, stream>>>(Qf, Kf, Vf, attn, vtb);
    k_out<<<dim3(64, 16), 256, 0, stream>>>(woT, vtb, b_out, out);  // x=m(64), y=n(16)
}